// Round 7
// baseline (833.897 us; speedup 1.0000x reference)
//
#include <hip/hip_runtime.h>

// Problem: VOCAB=32000, H=1024, L=256, B=64.  Only batch row 0 matters
// (reference broadcasts hs[:, :1, :]), so this is a single-sequence GRU.
//
// R2-R5: sentinel chunk-poll recurrence (128 blk x 8 waves) is the sync local
// optimum. R6: gi GEMV fused into poll idle time (k1 deleted, k2 725->610).
// R7: (a) barrier2 eliminated via double-buffered hlds — __syncthreads emits
// s_waitcnt vmcnt(0) before s_barrier, and barrier2 sat right after the e-row
// prefetch issue, draining ~600cy of fresh vmem on the chain EVERY step;
// (b) k3 fused: h2 is wave-uniform after the butterfly, so lane b scatter-stores
// feat[b][t*1024+hj] directly (8 sibling waves -> 8 consecutive floats -> 32B
// sector coalescing in L2).  k3 launch deleted.
#define SENT 0xAAAAAAAAu

typedef float f32x4 __attribute__((ext_vector_type(4)));

__device__ __forceinline__ float sigf(float x) { return 1.0f / (1.0f + __expf(-x)); }
__device__ __forceinline__ float tanh_fast(float x) {
  float e = __expf(2.0f * x);
  return 1.0f - 2.0f / (e + 1.0f);
}

// ---------- K2 v7: persistent recurrence, fused gi + fused feat broadcast ----------
// grid 128 x 512 (8 waves). Wave wv of block g owns h element hj = 8g+wv.
// Per lane in VGPRs: 3 w_hh row-chunks (48 f32) + 3 w_ih row-chunks (48 f32).
__global__ __launch_bounds__(512) void k2_rec(const int* __restrict__ x,
                                              const float* __restrict__ emb,
                                              const float* __restrict__ w_ih,
                                              const float* __restrict__ w_hh,
                                              const float* __restrict__ b_ih,
                                              const float* __restrict__ b_hh,
                                              const float* __restrict__ w_out,
                                              unsigned int* __restrict__ hseq,
                                              float* __restrict__ feat,
                                              float* __restrict__ acc)
{
  __shared__ float hlds[2][1024];   // 8 KB, double-buffered by t&1

  const int g    = blockIdx.x;
  const int tid  = threadIdx.x;
  const int wv   = tid >> 6;
  const int lane = tid & 63;
  const int hj   = __builtin_amdgcn_readfirstlane(g * 8 + wv);  // uniform -> s_loads

  // ---- w_hh into VGPRs: w[gate*4+j] holds row[j*256 + lane*4 .. +3] ----
  f32x4 w[12];
#pragma unroll
  for (int gate = 0; gate < 3; ++gate) {
    const float* row = w_hh + (size_t)(gate * 1024 + hj) * 1024;
#pragma unroll
    for (int j = 0; j < 4; ++j)
      w[gate * 4 + j] = *(const f32x4*)(row + j * 256 + lane * 4);
  }
  // ---- w_ih into VGPRs: same k-split (k = c*256 + lane*4 + i) ----
  f32x4 wi[12];
#pragma unroll
  for (int gate = 0; gate < 3; ++gate) {
    const float* row = w_ih + (size_t)(gate * 1024 + hj) * 1024;
#pragma unroll
    for (int c = 0; c < 4; ++c)
      wi[gate * 4 + c] = *(const f32x4*)(row + c * 256 + lane * 4);
  }

  const float br  = b_ih[hj]        + b_hh[hj];          // fold b_hh for r,z
  const float bz  = b_ih[1024 + hj] + b_hh[1024 + hj];
  const float bni = b_ih[2048 + hj];
  const float bnh = b_hh[2048 + hj];

  float hp = 0.0f, wout_acc = 0.0f;
  const unsigned long long* hs64 = (const unsigned long long*)hseq;
  float* featp = feat + ((size_t)lane << 18) + hj;       // feat[lane][.. + hj]

  // ---- gi for t=0 (e-row 0, coalesced: k = c*256 + lane*4) ----
  f32x4 ep[4];
  {
    const float* er = emb + (size_t)x[0] * 1024;
#pragma unroll
    for (int c = 0; c < 4; ++c) ep[c] = *(const f32x4*)(er + c * 256 + lane * 4);
  }
  float gir, giz, gin;
  {
    float d0 = 0.f, d1 = 0.f, d2 = 0.f;
#pragma unroll
    for (int c = 0; c < 4; ++c) {
      const f32x4 e4 = ep[c];
      const f32x4 wr = wi[c], wz4 = wi[4 + c], wn4 = wi[8 + c];
      d0 = fmaf(e4.x, wr.x, d0); d0 = fmaf(e4.y, wr.y, d0);
      d0 = fmaf(e4.z, wr.z, d0); d0 = fmaf(e4.w, wr.w, d0);
      d1 = fmaf(e4.x, wz4.x, d1); d1 = fmaf(e4.y, wz4.y, d1);
      d1 = fmaf(e4.z, wz4.z, d1); d1 = fmaf(e4.w, wz4.w, d1);
      d2 = fmaf(e4.x, wn4.x, d2); d2 = fmaf(e4.y, wn4.y, d2);
      d2 = fmaf(e4.z, wn4.z, d2); d2 = fmaf(e4.w, wn4.w, d2);
    }
#pragma unroll
    for (int m = 1; m < 64; m <<= 1) {
      d0 += __shfl_xor(d0, m, 64);
      d1 += __shfl_xor(d1, m, 64);
      d2 += __shfl_xor(d2, m, 64);
    }
    gir = d0 + br; giz = d1 + bz; gin = d2 + bni;
  }
  // issue e-row prefetch for t=1
  {
    const float* er = emb + (size_t)x[64] * 1024;
#pragma unroll
    for (int c = 0; c < 4; ++c) ep[c] = *(const f32x4*)(er + c * 256 + lane * 4);
  }

#pragma unroll 1
  for (int t = 0; t < 256; ++t) {
    const float wo = w_out[(size_t)t * 1024 + hj];   // wave-uniform scalar prefetch

    float ar = 0.f, az = 0.f, an = 0.f;

    if (t > 0) {
      // poll own 512 B chunk of row t-1: one coalesced plain dwordx2 (sc0 sc1) per
      // lane per round; a successful poll IS the data read.
      const unsigned long long* p = hs64 + (size_t)(t - 1) * 512 + wv * 64 + lane;
      unsigned long long v;
      for (;;) {
        asm volatile("global_load_dwordx2 %0, %1, off sc0 sc1\n\t"
                     "s_waitcnt vmcnt(0)"
                     : "=v"(v) : "v"(p) : "memory");
        const bool ok = (((unsigned int)v) != SENT) &
                        (((unsigned int)(v >> 32)) != SENT);
        if (__all(ok)) break;
      }
      float* hb = &hlds[t & 1][0];
      const int w0 = wv * 128 + lane * 2;          // 8B-aligned -> ds_write_b64
      hb[w0]     = __uint_as_float((unsigned int)v);
      hb[w0 + 1] = __uint_as_float((unsigned int)(v >> 32));
      // single barrier per step: placed BEFORE any fresh vmem issue, so its
      // implicit vmcnt(0) drain only waits on long-elapsed loads.
      __syncthreads();

      // dot: lane owns k = j*256 + lane*4 + c
#pragma unroll
      for (int j = 0; j < 4; ++j) {
        const f32x4 h4 = *(const f32x4*)&hb[j * 256 + lane * 4];
        const f32x4 wr = w[j], wz4 = w[4 + j], wn4 = w[8 + j];
        ar = fmaf(h4.x, wr.x, ar); ar = fmaf(h4.y, wr.y, ar);
        ar = fmaf(h4.z, wr.z, ar); ar = fmaf(h4.w, wr.w, ar);
        az = fmaf(h4.x, wz4.x, az); az = fmaf(h4.y, wz4.y, az);
        az = fmaf(h4.z, wz4.z, az); az = fmaf(h4.w, wz4.w, az);
        an = fmaf(h4.x, wn4.x, an); an = fmaf(h4.y, wn4.y, an);
        an = fmaf(h4.z, wn4.z, an); an = fmaf(h4.w, wn4.w, an);
      }
#pragma unroll
      for (int m = 1; m < 64; m <<= 1) {
        ar += __shfl_xor(ar, m, 64);
        az += __shfl_xor(az, m, 64);
        an += __shfl_xor(an, m, 64);
      }
    }

    const float r  = sigf(ar + gir);
    const float z  = sigf(az + giz);
    const float n  = tanh_fast(gin + r * (an + bnh));
    const float h2 = (1.0f - z) * n + z * hp;

    unsigned int bits = __float_as_uint(h2);
    if (bits == SENT) bits ^= 1u;                   // never store the sentinel
    hp = __uint_as_float(bits);

    if (lane == 0) {
      // fire-and-forget store to the coherence point
      unsigned int* vp = hseq + (size_t)t * 1024 + hj;
      asm volatile("global_store_dword %0, %1, off sc0 sc1"
                   :: "v"(vp), "v"(bits) : "memory");
      wout_acc = fmaf(hp, wo, wout_acc);            // fold w_out dot in
    }

    // fused feat broadcast: h2 is wave-uniform after the butterflies; lane b
    // stores feat[b][t*1024+hj].  Fire-and-forget, plain cached store.
    featp[(size_t)t << 10] = hp;

    // ---- fused gi for t+1 (tail work; e-loads drain at NEXT step's barrier,
    // after the poll spin, i.e. off the critical path) ----
    if (t < 255) {
      float d0 = 0.f, d1 = 0.f, d2 = 0.f;
#pragma unroll
      for (int c = 0; c < 4; ++c) {
        const f32x4 e4 = ep[c];
        const f32x4 wr = wi[c], wz4 = wi[4 + c], wn4 = wi[8 + c];
        d0 = fmaf(e4.x, wr.x, d0); d0 = fmaf(e4.y, wr.y, d0);
        d0 = fmaf(e4.z, wr.z, d0); d0 = fmaf(e4.w, wr.w, d0);
        d1 = fmaf(e4.x, wz4.x, d1); d1 = fmaf(e4.y, wz4.y, d1);
        d1 = fmaf(e4.z, wz4.z, d1); d1 = fmaf(e4.w, wz4.w, d1);
        d2 = fmaf(e4.x, wn4.x, d2); d2 = fmaf(e4.y, wn4.y, d2);
        d2 = fmaf(e4.z, wn4.z, d2); d2 = fmaf(e4.w, wn4.w, d2);
      }
#pragma unroll
      for (int m = 1; m < 64; m <<= 1) {
        d0 += __shfl_xor(d0, m, 64);
        d1 += __shfl_xor(d1, m, 64);
        d2 += __shfl_xor(d2, m, 64);
      }
      gir = d0 + br; giz = d1 + bz; gin = d2 + bni;
      if (t < 254) {                                // issue e-row for t+2
        const float* er = emb + (size_t)x[(t + 2) * 64] * 1024;
#pragma unroll
        for (int c = 0; c < 4; ++c) ep[c] = *(const f32x4*)(er + c * 256 + lane * 4);
      }
    }
  }

  if (lane == 0) atomicAdd(acc, wout_acc);
}

// ---------- K4: out[b] = sigmoid(acc + b_out) for all 64 b ----------
__global__ void k4_fin(const float* __restrict__ acc, const float* __restrict__ b_out,
                       float* __restrict__ outbuf)
{
  const float s = sigf(acc[0] + b_out[0]);
  outbuf[(size_t)16777216 + threadIdx.x] = s;
}

// ---------- launch ----------
extern "C" void kernel_launch(void* const* d_in, const int* in_sizes, int n_in,
                              void* d_out, int out_size, void* d_ws, size_t ws_size,
                              hipStream_t stream) {
  const int*   x     = (const int*)d_in[0];
  const float* emb   = (const float*)d_in[1];
  const float* w_ih  = (const float*)d_in[2];
  const float* w_hh  = (const float*)d_in[3];
  const float* b_ih  = (const float*)d_in[4];
  const float* b_hh  = (const float*)d_in[5];
  const float* w_out = (const float*)d_in[6];
  const float* b_out = (const float*)d_in[7];
  float* out = (float*)d_out;

  char* ws = (char*)d_ws;
  unsigned int* hseq = (unsigned int*)ws;                // 1,048,576 B
  float*        acc  = (float*)(ws + 1048576);           // 4 B

  hipMemsetAsync(hseq, 0xAA, (size_t)256 * 1024 * 4, stream);  // sentinel init
  hipMemsetAsync(acc, 0, 4, stream);

  hipLaunchKernelGGL(k2_rec, dim3(128), dim3(512), 0, stream,
                     x, emb, w_ih, w_hh, b_ih, b_hh, w_out, hseq, out, acc);
  hipLaunchKernelGGL(k4_fin, dim3(1), dim3(64), 0, stream, acc, b_out, out);
}